// Round 9
// baseline (437.508 us; speedup 1.0000x reference)
//
#include <hip/hip_runtime.h>
#include <math.h>

// Problem constants
#define N_TOK 131072   // 32*64*64 tokens
#define D     64       // embedding dim
#define K     1024     // codebook size

// Output layout (floats, concatenated in reference return order):
#define OUT_LOSS  8388608
#define OUT_IDX   8388609
#define OUT_PERP  8519681

// ws layout (bytes):
//   0        counts  u32[1024]
//   4096     enorm   f32[1024]  np-exact ||e||^2
//   8192     sinit   f32[1024]  fp64-accurate ||e||^2 (screen C-init)
//   12288    sse     f32
//   12292    rcnt    u32        rescue-list counter
//   16384    w_hi    s16[65536] bf16 hi split of w (128 KB)
//   147456   w_lo    s16[65536] bf16 lo split of w (128 KB)
//   278528   win     i32[131072] packed winner (bit31 = needs rescue)
//   802816   rlist   i32[131072] compacted rescue token ids

#define W_WINDOW 1e-4f

typedef short bf16x8 __attribute__((ext_vector_type(8)));
typedef float f32x4  __attribute__((ext_vector_type(4)));

// ---------------------------------------------------------------------------
__device__ __forceinline__ float np_pairsum64(const float* sq) {
    float r[8];
#pragma unroll
    for (int j = 0; j < 8; ++j) r[j] = sq[j];
#pragma unroll
    for (int i = 8; i < 64; i += 8) {
#pragma unroll
        for (int j = 0; j < 8; ++j) r[j] = __fadd_rn(r[j], sq[i + j]);
    }
    return __fadd_rn(
        __fadd_rn(__fadd_rn(r[0], r[1]), __fadd_rn(r[2], r[3])),
        __fadd_rn(__fadd_rn(r[4], r[5]), __fadd_rn(r[6], r[7])));
}

__device__ __forceinline__ short bf16_trunc(float f) {
    return (short)(__float_as_uint(f) >> 16);
}
__device__ __forceinline__ float bf16_up(short s) {
    return __uint_as_float(((unsigned)(unsigned short)s) << 16);
}

// ---------------------------------------------------------------------------
__global__ void vq_prep(const float* __restrict__ w,
                        float* __restrict__ enorm,
                        float* __restrict__ sinit,
                        short* __restrict__ w_hi,
                        short* __restrict__ w_lo,
                        unsigned* __restrict__ counts,
                        float* __restrict__ sse,
                        unsigned* __restrict__ rcnt) {
    int k = blockIdx.x * blockDim.x + threadIdx.x;
    if (k < K) {
        const float* wr = w + (size_t)k * D;
        float sq[D];
        double acc = 0.0;
#pragma unroll
        for (int i = 0; i < D; ++i) {
            float v = wr[i];
            sq[i] = __fmul_rn(v, v);
            acc += (double)v * (double)v;
            short hi = bf16_trunc(v);
            float res = v - bf16_up(hi);
            short lo = bf16_trunc(res);
            w_hi[(size_t)k * D + i] = hi;
            w_lo[(size_t)k * D + i] = lo;
        }
        enorm[k] = np_pairsum64(sq);
        sinit[k] = (float)acc;
        counts[k] = 0u;
    }
    if (k == 0) { *sse = 0.f; *rcnt = 0u; }
}

// ---------------------------------------------------------------------------
// Screen ONLY. 4 independent waves/block, wave = 32 tokens (2 M-tiles).
// Single MFMA pass, in-register top-2, packed winner+rescue-flag to ws.
// No barriers, no epilogue, no atomics.
// ---------------------------------------------------------------------------
#define MFMA(A, B, C) __builtin_amdgcn_mfma_f32_16x16x32_bf16(A, B, C, 0, 0, 0)

__global__ __launch_bounds__(256, 2)
void vq_screen(const float* __restrict__ x,
               const float* __restrict__ sinit,
               const short* __restrict__ w_hi,
               const short* __restrict__ w_lo,
               int* __restrict__ win) {
    const int lane = threadIdx.x & 63;
    const int wv   = __builtin_amdgcn_readfirstlane(threadIdx.x >> 6);
    const int quad = lane >> 4;
    const int col  = lane & 15;
    const int tokWave = blockIdx.x * 128 + wv * 32;

    // A fragments: bf16 hi/lo splits of (-2x), 2 M-tiles.
    bf16x8 Ah[2][2], Al[2][2];
#pragma unroll
    for (int mt = 0; mt < 2; ++mt) {
#pragma unroll
        for (int ks = 0; ks < 2; ++ks) {
            const float4* ap = (const float4*)(x + (size_t)(tokWave + mt * 16 + col) * D
                                               + ks * 32 + quad * 8);
            float4 u0 = ap[0], u1 = ap[1];
            float f[8] = {u0.x, u0.y, u0.z, u0.w, u1.x, u1.y, u1.z, u1.w};
            bf16x8 h, l;
#pragma unroll
            for (int j = 0; j < 8; ++j) {
                float v = -2.0f * f[j];
                short hi = bf16_trunc(v);
                float res = v - bf16_up(hi);
                h[j] = hi;
                l[j] = bf16_trunc(res);
            }
            Ah[mt][ks] = h;
            Al[mt][ks] = l;
        }
    }

    float m1[8], m2[8];
    int   i1[8];
#pragma unroll
    for (int s = 0; s < 8; ++s) { m1[s] = INFINITY; m2[s] = INFINITY; i1[s] = 0; }

    for (int tile = 0; tile < 64; ++tile) {
        const int cbase = tile * 16;
        const size_t rowoff = (size_t)(cbase + col) * D;
        bf16x8 Bh0 = *(const bf16x8*)(w_hi + rowoff + 0 * 32 + quad * 8);
        bf16x8 Bh1 = *(const bf16x8*)(w_hi + rowoff + 1 * 32 + quad * 8);
        bf16x8 Bl0 = *(const bf16x8*)(w_lo + rowoff + 0 * 32 + quad * 8);
        bf16x8 Bl1 = *(const bf16x8*)(w_lo + rowoff + 1 * 32 + quad * 8);
        float si = sinit[cbase + col];
        f32x4 C0 = {si, si, si, si};
        f32x4 C1 = {si, si, si, si};
        C0 = MFMA(Ah[0][0], Bh0, C0); C0 = MFMA(Ah[0][1], Bh1, C0);
        C0 = MFMA(Ah[0][0], Bl0, C0); C0 = MFMA(Ah[0][1], Bl1, C0);
        C0 = MFMA(Al[0][0], Bh0, C0); C0 = MFMA(Al[0][1], Bh1, C0);
        C1 = MFMA(Ah[1][0], Bh0, C1); C1 = MFMA(Ah[1][1], Bh1, C1);
        C1 = MFMA(Ah[1][0], Bl0, C1); C1 = MFMA(Ah[1][1], Bl1, C1);
        C1 = MFMA(Al[1][0], Bh0, C1); C1 = MFMA(Al[1][1], Bh1, C1);

        const int code = cbase + col;
#pragma unroll
        for (int r = 0; r < 4; ++r) {
            {
                float c = C0[r];
                m2[r] = fminf(m2[r], fmaxf(m1[r], c));
                bool lt = c < m1[r];
                i1[r] = lt ? code : i1[r];
                m1[r] = fminf(m1[r], c);
            }
            {
                float c = C1[r];
                m2[4 + r] = fminf(m2[4 + r], fmaxf(m1[4 + r], c));
                bool lt = c < m1[4 + r];
                i1[4 + r] = lt ? code : i1[4 + r];
                m1[4 + r] = fminf(m1[4 + r], c);
            }
        }
    }

    // Cross-lane top-2 merge over the 16 cols of each quad.
#pragma unroll
    for (int s = 0; s < 8; ++s) {
#pragma unroll
        for (int msk = 1; msk <= 8; msk <<= 1) {
            float om1 = __shfl_xor(m1[s], msk, 64);
            int   oi1 = __shfl_xor(i1[s], msk, 64);
            float om2 = __shfl_xor(m2[s], msk, 64);
            float nm2 = fminf(fmaxf(m1[s], om1), fminf(m2[s], om2));
            bool  take = om1 < m1[s];
            m1[s] = take ? om1 : m1[s];
            i1[s] = take ? oi1 : i1[s];
            m2[s] = nm2;
        }
    }

    if (col == 0) {
#pragma unroll
        for (int s = 0; s < 8; ++s) {
            int tl = (s >> 2) * 16 + quad * 4 + (s & 3);
            bool resc = (m2[s] <= m1[s] + W_WINDOW);
            win[tokWave + tl] = resc ? (i1[s] | 0x80000000) : i1[s];
        }
    }
}
#undef MFMA

// ---------------------------------------------------------------------------
// Epilogue: 1 thread/token, full grid parallelism. Direct winners: gather +
// write + SSE + counts. Rescue tokens: compact into global list.
// ---------------------------------------------------------------------------
__global__ __launch_bounds__(256, 4)
void vq_epi(const float* __restrict__ x,
            const float* __restrict__ w,
            const int* __restrict__ win,
            float* __restrict__ out,
            unsigned* __restrict__ counts,
            float* __restrict__ sse,
            int* __restrict__ rlist,
            unsigned* __restrict__ rcnt) {
    const int t = blockIdx.x * 256 + threadIdx.x;
    const int wi = win[t];
    float err = 0.f;
    if (wi < 0) {
        unsigned u = atomicAdd(rcnt, 1u);
        rlist[u] = t;
    } else {
        const float4* qr  = (const float4*)(w + (size_t)wi * D);
        const float4* xp2 = (const float4*)(x + (size_t)t * D);
        float4*       oq  = (float4*)(out + (size_t)t * D);
#pragma unroll
        for (int i = 0; i < 16; ++i) {
            float4 q = qr[i];
            float4 xv = xp2[i];
            float e0 = q.x - xv.x, e1 = q.y - xv.y;
            float e2 = q.z - xv.z, e3 = q.w - xv.w;
            err = fmaf(e0, e0, err);
            err = fmaf(e1, e1, err);
            err = fmaf(e2, e2, err);
            err = fmaf(e3, e3, err);
            oq[i] = q;
        }
        out[OUT_IDX + t] = (float)wi;
        atomicAdd(&counts[wi], 1u);
    }
#pragma unroll
    for (int o = 32; o > 0; o >>= 1) err += __shfl_down(err, o, 64);
    if ((threadIdx.x & 63) == 0) atomicAdd(sse, err);
}

// ---------------------------------------------------------------------------
// Rescue: 1024 waves stride the compacted list; np-exact full 1024-code scan
// per token (bit-verified in rounds 6-8).
// ---------------------------------------------------------------------------
__global__ __launch_bounds__(256, 4)
void vq_rescue(const float* __restrict__ x,
               const float* __restrict__ w,
               const float* __restrict__ enorm,
               float* __restrict__ out,
               unsigned* __restrict__ counts,
               float* __restrict__ sse,
               const int* __restrict__ rlist,
               const unsigned* __restrict__ rcnt) {
    const int lane = threadIdx.x & 63;
    const unsigned g = blockIdx.x * 4 + (threadIdx.x >> 6);
    const unsigned n = *rcnt;

    for (unsigned u = g; u < n; u += 1024) {
        const int t = rlist[u];

        const float4* xp = (const float4*)(x + (size_t)t * D);
        float4 v[16];
#pragma unroll
        for (int i = 0; i < 16; ++i) v[i] = xp[i];

        // Sx np-exact (8 accumulators, ascending order).
        float r0, r1, r2, r3, r4, r5, r6, r7;
        r0 = __fmul_rn(v[0].x, v[0].x); r1 = __fmul_rn(v[0].y, v[0].y);
        r2 = __fmul_rn(v[0].z, v[0].z); r3 = __fmul_rn(v[0].w, v[0].w);
        r4 = __fmul_rn(v[1].x, v[1].x); r5 = __fmul_rn(v[1].y, v[1].y);
        r6 = __fmul_rn(v[1].z, v[1].z); r7 = __fmul_rn(v[1].w, v[1].w);
#pragma unroll
        for (int i = 2; i < 16; i += 2) {
            r0 = __fadd_rn(r0, __fmul_rn(v[i].x, v[i].x));
            r1 = __fadd_rn(r1, __fmul_rn(v[i].y, v[i].y));
            r2 = __fadd_rn(r2, __fmul_rn(v[i].z, v[i].z));
            r3 = __fadd_rn(r3, __fmul_rn(v[i].w, v[i].w));
            r4 = __fadd_rn(r4, __fmul_rn(v[i + 1].x, v[i + 1].x));
            r5 = __fadd_rn(r5, __fmul_rn(v[i + 1].y, v[i + 1].y));
            r6 = __fadd_rn(r6, __fmul_rn(v[i + 1].z, v[i + 1].z));
            r7 = __fadd_rn(r7, __fmul_rn(v[i + 1].w, v[i + 1].w));
        }
        float Sx = __fadd_rn(
            __fadd_rn(__fadd_rn(r0, r1), __fadd_rn(r2, r3)),
            __fadd_rn(__fadd_rn(r4, r5), __fadd_rn(r6, r7)));

        float bestd = INFINITY;
        int   bestc = 0x7fffffff;
        for (int j = 0; j < 16; ++j) {
            int c = j * 64 + lane;
            const float4* wr4 = (const float4*)(w + (size_t)c * D);
            float a = 0.f;
#pragma unroll
            for (int i = 0; i < 16; ++i) {
                float4 q = wr4[i];
                a = __fmaf_rn(q.x, v[i].x, a);
                a = __fmaf_rn(q.y, v[i].y, a);
                a = __fmaf_rn(q.z, v[i].z, a);
                a = __fmaf_rn(q.w, v[i].w, a);
            }
            float dist = __fsub_rn(__fadd_rn(Sx, enorm[c]), __fmul_rn(2.0f, a));
            if (dist < bestd || (dist == bestd && c < bestc)) {
                bestd = dist; bestc = c;
            }
        }
#pragma unroll
        for (int msk = 1; msk <= 32; msk <<= 1) {
            float od = __shfl_xor(bestd, msk, 64);
            int   oc = __shfl_xor(bestc, msk, 64);
            bool take = (od < bestd) || (od == bestd && oc < bestc);
            bestd = take ? od : bestd;
            bestc = take ? oc : bestc;
        }

        float qv = w[(size_t)bestc * D + lane];
        float xv = x[(size_t)t * D + lane];
        float e  = qv - xv;
        float err = e * e;
        out[(size_t)t * D + lane] = qv;
#pragma unroll
        for (int o = 32; o > 0; o >>= 1) err += __shfl_down(err, o, 64);
        if (lane == 0) {
            atomicAdd(sse, err);
            out[OUT_IDX + t] = (float)bestc;
            atomicAdd(&counts[bestc], 1u);
        }
    }
}

// ---------------------------------------------------------------------------
__global__ void vq_fin(const unsigned* __restrict__ counts,
                       const float* __restrict__ sse,
                       float* __restrict__ out) {
    __shared__ float red[256];
    float s = 0.f;
    for (int k = threadIdx.x; k < K; k += 256) {
        float p = (float)counts[k] * (1.0f / (float)N_TOK);
        s += p * logf(p + 1e-10f);
    }
    red[threadIdx.x] = s;
    __syncthreads();
    for (int st = 128; st > 0; st >>= 1) {
        if (threadIdx.x < st) red[threadIdx.x] += red[threadIdx.x + st];
        __syncthreads();
    }
    if (threadIdx.x == 0) {
        out[OUT_PERP] = expf(-red[0]);
        out[OUT_LOSS] = 1.25f * (*sse) * (1.0f / 8388608.0f);  // (1+0.25)*MSE
    }
}

// ---------------------------------------------------------------------------
extern "C" void kernel_launch(void* const* d_in, const int* in_sizes, int n_in,
                              void* d_out, int out_size, void* d_ws, size_t ws_size,
                              hipStream_t stream) {
    const float* x = (const float*)d_in[0];  // [32,64,64,64] fp32
    const float* w = (const float*)d_in[1];  // [1024,64] fp32
    float* out = (float*)d_out;

    char* ws = (char*)d_ws;
    unsigned* counts = (unsigned*)(ws + 0);
    float*    enorm  = (float*)(ws + 4096);
    float*    sinit  = (float*)(ws + 8192);
    float*    sse    = (float*)(ws + 12288);
    unsigned* rcnt   = (unsigned*)(ws + 12292);
    short*    w_hi   = (short*)(ws + 16384);
    short*    w_lo   = (short*)(ws + 147456);
    int*      win    = (int*)(ws + 278528);
    int*      rlist  = (int*)(ws + 802816);

    vq_prep<<<4, 256, 0, stream>>>(w, enorm, sinit, w_hi, w_lo, counts, sse, rcnt);
    vq_screen<<<N_TOK / 128, 256, 0, stream>>>(x, sinit, w_hi, w_lo, win);
    vq_epi<<<N_TOK / 256, 256, 0, stream>>>(x, w, win, out, counts, sse, rlist, rcnt);
    vq_rescue<<<256, 256, 0, stream>>>(x, w, enorm, out, counts, sse, rlist, rcnt);
    vq_fin<<<1, 256, 0, stream>>>(counts, sse, out);
}

// Round 10
// 342.176 us; speedup vs baseline: 1.2786x; 1.2786x over previous
//
#include <hip/hip_runtime.h>
#include <math.h>

// Problem constants
#define N_TOK 131072   // 32*64*64 tokens
#define D     64       // embedding dim
#define K     1024     // codebook size

// Output layout (floats, concatenated in reference return order):
#define OUT_LOSS  8388608
#define OUT_IDX   8388609
#define OUT_PERP  8519681

// ws layout (bytes):
//   0        counts  u32[1024]
//   4096     enorm   f32[1024]  np-exact ||e||^2
//   8192     sinit   f32[1024]  fp64-accurate ||e||^2 (screen C-init)
//   12288    sse     f32
//   12292    rcnt    u32        rescue-list counter
//   16384    w_hi    s16[65536] bf16 hi split of w (128 KB)
//   147456   w_lo    s16[65536] bf16 lo split of w (128 KB)
//   278528   win     i32[131072] packed winner (bit31 = needs rescue)
//   802816   rlist   i32[131072] compacted rescue token ids

#define W_WINDOW 1e-4f

typedef short bf16x8 __attribute__((ext_vector_type(8)));
typedef float f32x4  __attribute__((ext_vector_type(4)));
typedef float vf16   __attribute__((ext_vector_type(16)));

// ---------------------------------------------------------------------------
__device__ __forceinline__ float np_pairsum64(const float* sq) {
    float r[8];
#pragma unroll
    for (int j = 0; j < 8; ++j) r[j] = sq[j];
#pragma unroll
    for (int i = 8; i < 64; i += 8) {
#pragma unroll
        for (int j = 0; j < 8; ++j) r[j] = __fadd_rn(r[j], sq[i + j]);
    }
    return __fadd_rn(
        __fadd_rn(__fadd_rn(r[0], r[1]), __fadd_rn(r[2], r[3])),
        __fadd_rn(__fadd_rn(r[4], r[5]), __fadd_rn(r[6], r[7])));
}

__device__ __forceinline__ short bf16_trunc(float f) {
    return (short)(__float_as_uint(f) >> 16);
}
__device__ __forceinline__ float bf16_up(short s) {
    return __uint_as_float(((unsigned)(unsigned short)s) << 16);
}

// ---------------------------------------------------------------------------
__global__ void vq_prep(const float* __restrict__ w,
                        float* __restrict__ enorm,
                        float* __restrict__ sinit,
                        short* __restrict__ w_hi,
                        short* __restrict__ w_lo,
                        unsigned* __restrict__ counts,
                        float* __restrict__ sse,
                        unsigned* __restrict__ rcnt) {
    int k = blockIdx.x * blockDim.x + threadIdx.x;
    if (k < K) {
        const float* wr = w + (size_t)k * D;
        float sq[D];
        double acc = 0.0;
#pragma unroll
        for (int i = 0; i < D; ++i) {
            float v = wr[i];
            sq[i] = __fmul_rn(v, v);
            acc += (double)v * (double)v;
            short hi = bf16_trunc(v);
            float res = v - bf16_up(hi);
            short lo = bf16_trunc(res);
            w_hi[(size_t)k * D + i] = hi;
            w_lo[(size_t)k * D + i] = lo;
        }
        enorm[k] = np_pairsum64(sq);
        sinit[k] = (float)acc;
        counts[k] = 0u;
    }
    if (k == 0) { *sse = 0.f; *rcnt = 0u; }
}

// ---------------------------------------------------------------------------
// Screen ONLY (round-8/9 verified math). 4 waves/block, wave = 32 tokens.
// Single MFMA pass, in-register top-2, packed winner+rescue-flag to ws.
// ---------------------------------------------------------------------------
#define MFMA(A, B, C) __builtin_amdgcn_mfma_f32_16x16x32_bf16(A, B, C, 0, 0, 0)

__global__ __launch_bounds__(256, 4)
void vq_screen(const float* __restrict__ x,
               const float* __restrict__ sinit,
               const short* __restrict__ w_hi,
               const short* __restrict__ w_lo,
               int* __restrict__ win) {
    const int lane = threadIdx.x & 63;
    const int wv   = __builtin_amdgcn_readfirstlane(threadIdx.x >> 6);
    const int quad = lane >> 4;
    const int col  = lane & 15;
    const int tokWave = blockIdx.x * 128 + wv * 32;

    bf16x8 Ah[2][2], Al[2][2];
#pragma unroll
    for (int mt = 0; mt < 2; ++mt) {
#pragma unroll
        for (int ks = 0; ks < 2; ++ks) {
            const float4* ap = (const float4*)(x + (size_t)(tokWave + mt * 16 + col) * D
                                               + ks * 32 + quad * 8);
            float4 u0 = ap[0], u1 = ap[1];
            float f[8] = {u0.x, u0.y, u0.z, u0.w, u1.x, u1.y, u1.z, u1.w};
            bf16x8 h, l;
#pragma unroll
            for (int j = 0; j < 8; ++j) {
                float v = -2.0f * f[j];
                short hi = bf16_trunc(v);
                float res = v - bf16_up(hi);
                h[j] = hi;
                l[j] = bf16_trunc(res);
            }
            Ah[mt][ks] = h;
            Al[mt][ks] = l;
        }
    }

    float m1[8], m2[8];
    int   i1[8];
#pragma unroll
    for (int s = 0; s < 8; ++s) { m1[s] = INFINITY; m2[s] = INFINITY; i1[s] = 0; }

    for (int tile = 0; tile < 64; ++tile) {
        const int cbase = tile * 16;
        const size_t rowoff = (size_t)(cbase + col) * D;
        bf16x8 Bh0 = *(const bf16x8*)(w_hi + rowoff + 0 * 32 + quad * 8);
        bf16x8 Bh1 = *(const bf16x8*)(w_hi + rowoff + 1 * 32 + quad * 8);
        bf16x8 Bl0 = *(const bf16x8*)(w_lo + rowoff + 0 * 32 + quad * 8);
        bf16x8 Bl1 = *(const bf16x8*)(w_lo + rowoff + 1 * 32 + quad * 8);
        float si = sinit[cbase + col];
        f32x4 C0 = {si, si, si, si};
        f32x4 C1 = {si, si, si, si};
        C0 = MFMA(Ah[0][0], Bh0, C0); C0 = MFMA(Ah[0][1], Bh1, C0);
        C0 = MFMA(Ah[0][0], Bl0, C0); C0 = MFMA(Ah[0][1], Bl1, C0);
        C0 = MFMA(Al[0][0], Bh0, C0); C0 = MFMA(Al[0][1], Bh1, C0);
        C1 = MFMA(Ah[1][0], Bh0, C1); C1 = MFMA(Ah[1][1], Bh1, C1);
        C1 = MFMA(Ah[1][0], Bl0, C1); C1 = MFMA(Ah[1][1], Bl1, C1);
        C1 = MFMA(Al[1][0], Bh0, C1); C1 = MFMA(Al[1][1], Bh1, C1);

        const int code = cbase + col;
#pragma unroll
        for (int r = 0; r < 4; ++r) {
            {
                float c = C0[r];
                m2[r] = fminf(m2[r], fmaxf(m1[r], c));
                bool lt = c < m1[r];
                i1[r] = lt ? code : i1[r];
                m1[r] = fminf(m1[r], c);
            }
            {
                float c = C1[r];
                m2[4 + r] = fminf(m2[4 + r], fmaxf(m1[4 + r], c));
                bool lt = c < m1[4 + r];
                i1[4 + r] = lt ? code : i1[4 + r];
                m1[4 + r] = fminf(m1[4 + r], c);
            }
        }
    }

#pragma unroll
    for (int s = 0; s < 8; ++s) {
#pragma unroll
        for (int msk = 1; msk <= 8; msk <<= 1) {
            float om1 = __shfl_xor(m1[s], msk, 64);
            int   oi1 = __shfl_xor(i1[s], msk, 64);
            float om2 = __shfl_xor(m2[s], msk, 64);
            float nm2 = fminf(fmaxf(m1[s], om1), fminf(m2[s], om2));
            bool  take = om1 < m1[s];
            m1[s] = take ? om1 : m1[s];
            i1[s] = take ? oi1 : i1[s];
            m2[s] = nm2;
        }
    }

    if (col == 0) {
#pragma unroll
        for (int s = 0; s < 8; ++s) {
            int tl = (s >> 2) * 16 + quad * 4 + (s & 3);
            bool resc = (m2[s] <= m1[s] + W_WINDOW);
            win[tokWave + tl] = resc ? (i1[s] | 0x80000000) : i1[s];
        }
    }
}
#undef MFMA

// ---------------------------------------------------------------------------
// Epilogue: 1 thread/token. Direct winners: gather+write+SSE+counts.
// Rescue tokens: compact into global list.
// ---------------------------------------------------------------------------
__global__ __launch_bounds__(256, 4)
void vq_epi(const float* __restrict__ x,
            const float* __restrict__ w,
            const int* __restrict__ win,
            float* __restrict__ out,
            unsigned* __restrict__ counts,
            float* __restrict__ sse,
            int* __restrict__ rlist,
            unsigned* __restrict__ rcnt) {
    const int t = blockIdx.x * 256 + threadIdx.x;
    const int wi = win[t];
    float err = 0.f;
    if (wi < 0) {
        unsigned u = atomicAdd(rcnt, 1u);
        rlist[u] = t;
    } else {
        const float4* qr  = (const float4*)(w + (size_t)wi * D);
        const float4* xp2 = (const float4*)(x + (size_t)t * D);
        float4*       oq  = (float4*)(out + (size_t)t * D);
#pragma unroll
        for (int i = 0; i < 16; ++i) {
            float4 q = qr[i];
            float4 xv = xp2[i];
            float e0 = q.x - xv.x, e1 = q.y - xv.y;
            float e2 = q.z - xv.z, e3 = q.w - xv.w;
            err = fmaf(e0, e0, err);
            err = fmaf(e1, e1, err);
            err = fmaf(e2, e2, err);
            err = fmaf(e3, e3, err);
            oq[i] = q;
        }
        out[OUT_IDX + t] = (float)wi;
        atomicAdd(&counts[wi], 1u);
    }
#pragma unroll
    for (int o = 32; o > 0; o >>= 1) err += __shfl_down(err, o, 64);
    if ((threadIdx.x & 63) == 0) atomicAdd(sse, err);
}

// ---------------------------------------------------------------------------
// Rescue v2 (round-5-verified structure on the compacted list).
// Block = 1024 threads = 16 waves = 64 tokens (lane = token); wave wv scans
// codes [wv*64, wv*64+64) with the np-exact fp32 chain, wave-uniform scalar
// w loads. LDS first-min combine in ascending chunk order == np.argmin.
// ---------------------------------------------------------------------------
#define XR(d) ((d) < 16 ? xa[(d) & 15] : (d) < 32 ? xb[(d) & 15] \
              : (d) < 48 ? xc[(d) & 15] : xd[(d) & 15])

__global__ __launch_bounds__(1024, 1)
void vq_rescue(const float* __restrict__ x,
               const float* __restrict__ w,
               const float* __restrict__ enorm,
               float* __restrict__ out,
               unsigned* __restrict__ counts,
               float* __restrict__ sse,
               const int* __restrict__ rlist,
               const unsigned* __restrict__ rcnt) {
    const int lane = threadIdx.x & 63;
    const int wv   = __builtin_amdgcn_readfirstlane(threadIdx.x >> 6);  // 0..15
    const unsigned n = *rcnt;

    __shared__ float sd[16][64];
    __shared__ int   si[16][64];

    for (unsigned g = blockIdx.x; g * 64u < n; g += 256u) {
        const unsigned slot = g * 64u + (unsigned)lane;
        const bool valid = slot < n;
        const int t = valid ? rlist[slot] : 0;

        // Token row in 4 SSA vectors.
        const vf16* xp = (const vf16*)(x + (size_t)t * D);
        vf16 xa = xp[0], xb = xp[1], xc = xp[2], xd = xp[3];

        // Sx np-exact (8 accumulators, ascending blocks, pairwise tail).
        float Sx;
        {
            float r0, r1, r2, r3, r4, r5, r6, r7;
#define SQ(n) __fmul_rn(XR(n), XR(n))
            r0 = SQ(0); r1 = SQ(1); r2 = SQ(2); r3 = SQ(3);
            r4 = SQ(4); r5 = SQ(5); r6 = SQ(6); r7 = SQ(7);
#define ACC8(i)                                                           \
            r0 = __fadd_rn(r0, SQ(8*(i)+0)); r1 = __fadd_rn(r1, SQ(8*(i)+1)); \
            r2 = __fadd_rn(r2, SQ(8*(i)+2)); r3 = __fadd_rn(r3, SQ(8*(i)+3)); \
            r4 = __fadd_rn(r4, SQ(8*(i)+4)); r5 = __fadd_rn(r5, SQ(8*(i)+5)); \
            r6 = __fadd_rn(r6, SQ(8*(i)+6)); r7 = __fadd_rn(r7, SQ(8*(i)+7));
            ACC8(1) ACC8(2) ACC8(3) ACC8(4) ACC8(5) ACC8(6) ACC8(7)
            Sx = __fadd_rn(
                __fadd_rn(__fadd_rn(r0, r1), __fadd_rn(r2, r3)),
                __fadd_rn(__fadd_rn(r4, r5), __fadd_rn(r6, r7)));
#undef ACC8
#undef SQ
        }

        // np-exact scan of this wave's 64-code chunk (c ascending).
        float best = INFINITY;
        int   bidx = 0x7fffffff;
        const int c0 = wv * 64;
        for (int cc = 0; cc < 64; ++cc) {
            const int c = c0 + cc;
            const float* __restrict__ wr = w + (size_t)c * D;  // wave-uniform
            float a = 0.f;
#pragma unroll
            for (int d = 0; d < D; ++d) a = __fmaf_rn(wr[d], XR(d), a);
            float dist = __fsub_rn(__fadd_rn(Sx, enorm[c]), __fmul_rn(2.0f, a));
            bool lt = dist < best;  // strict <: first-min within chunk
            best = lt ? dist : best;
            bidx = lt ? c : bidx;
        }
        sd[wv][lane] = best;
        si[wv][lane] = bidx;
        __syncthreads();

        if (wv == 0) {
            float b  = sd[0][lane];
            int   bi = si[0][lane];
#pragma unroll
            for (int j = 1; j < 16; ++j) {
                float dj = sd[j][lane];
                bool  l  = dj < b;  // strict <: lower chunk (lower idx) wins ties
                b  = l ? dj : b;
                bi = l ? si[j][lane] : bi;
            }

            float err = 0.f;
            if (valid) {
                const float4* qr = (const float4*)(w + (size_t)bi * D);
                float4*       oq = (float4*)(out + (size_t)t * D);
#pragma unroll
                for (int i = 0; i < 16; ++i) {
                    float4 q = qr[i];
                    float e0 = q.x - XR(4 * i + 0);
                    float e1 = q.y - XR(4 * i + 1);
                    float e2 = q.z - XR(4 * i + 2);
                    float e3 = q.w - XR(4 * i + 3);
                    err = fmaf(e0, e0, err);
                    err = fmaf(e1, e1, err);
                    err = fmaf(e2, e2, err);
                    err = fmaf(e3, e3, err);
                    oq[i] = q;
                }
                out[OUT_IDX + t] = (float)bi;
                atomicAdd(&counts[bi], 1u);
            }
#pragma unroll
            for (int o = 32; o > 0; o >>= 1) err += __shfl_down(err, o, 64);
            if (lane == 0) atomicAdd(sse, err);
        }
        __syncthreads();
    }
}
#undef XR

// ---------------------------------------------------------------------------
__global__ void vq_fin(const unsigned* __restrict__ counts,
                       const float* __restrict__ sse,
                       float* __restrict__ out) {
    __shared__ float red[256];
    float s = 0.f;
    for (int k = threadIdx.x; k < K; k += 256) {
        float p = (float)counts[k] * (1.0f / (float)N_TOK);
        s += p * logf(p + 1e-10f);
    }
    red[threadIdx.x] = s;
    __syncthreads();
    for (int st = 128; st > 0; st >>= 1) {
        if (threadIdx.x < st) red[threadIdx.x] += red[threadIdx.x + st];
        __syncthreads();
    }
    if (threadIdx.x == 0) {
        out[OUT_PERP] = expf(-red[0]);
        out[OUT_LOSS] = 1.25f * (*sse) * (1.0f / 8388608.0f);  // (1+0.25)*MSE
    }
}

// ---------------------------------------------------------------------------
extern "C" void kernel_launch(void* const* d_in, const int* in_sizes, int n_in,
                              void* d_out, int out_size, void* d_ws, size_t ws_size,
                              hipStream_t stream) {
    const float* x = (const float*)d_in[0];  // [32,64,64,64] fp32
    const float* w = (const float*)d_in[1];  // [1024,64] fp32
    float* out = (float*)d_out;

    char* ws = (char*)d_ws;
    unsigned* counts = (unsigned*)(ws + 0);
    float*    enorm  = (float*)(ws + 4096);
    float*    sinit  = (float*)(ws + 8192);
    float*    sse    = (float*)(ws + 12288);
    unsigned* rcnt   = (unsigned*)(ws + 12292);
    short*    w_hi   = (short*)(ws + 16384);
    short*    w_lo   = (short*)(ws + 147456);
    int*      win    = (int*)(ws + 278528);
    int*      rlist  = (int*)(ws + 802816);

    vq_prep<<<4, 256, 0, stream>>>(w, enorm, sinit, w_hi, w_lo, counts, sse, rcnt);
    vq_screen<<<N_TOK / 128, 256, 0, stream>>>(x, sinit, w_hi, w_lo, win);
    vq_epi<<<N_TOK / 256, 256, 0, stream>>>(x, w, win, out, counts, sse, rlist, rcnt);
    vq_rescue<<<256, 1024, 0, stream>>>(x, w, enorm, out, counts, sse, rlist, rcnt);
    vq_fin<<<1, 256, 0, stream>>>(counts, sse, out);
}